// Round 4
// baseline (820.146 us; speedup 1.0000x reference)
//
#include <hip/hip_runtime.h>
#include <hip/hip_cooperative_groups.h>
namespace cg = cooperative_groups;

#define N 8
#define L 6400
#define C 256
#define K 100

// ===================== cooperative mega-kernel =============================
// grid = 1024 blocks x 256 threads, 4 blocks/CU co-resident.
// Phase A: 1024 jobs: seg = b>>6 (16 segs = n*2+half), piece = b&63,
//          each job sums 100 rows x 100 cols of prob into P[b][100] (fp64).
// Phase B: blocks 0..7: combine 64+64 piece-partials, theta0*theta1, argmax.
// Phase C: waves 0..799: one 64-wide ballot word of topics[:, :L, k*] > 0.5.
// Phase D: blocks 0..7: popc + prefix over 100 words -> woffs/lenbuf.
// Phase E: 4096 waves x ~12.5 rows: scatter selected feat rows, zero tail,
//          plus coalesced float4 mask write.
__global__ void __launch_bounds__(256, 4)
mega(const float* __restrict__ feat,
     const float* __restrict__ prob,
     const float* __restrict__ topics,
     double* __restrict__ P,                 // [1024][100]
     unsigned long long* __restrict__ bits,  // [800]
     int* __restrict__ woffs,                // [800]
     int* __restrict__ kstar,                // [8]
     int* __restrict__ lenbuf,               // [8]
     float* __restrict__ out)
{
    cg::grid_group grid = cg::this_grid();
    const int bid = blockIdx.x;
    const int t   = threadIdx.x;

    // ---------------- Phase A: partial column sums ------------------------
    {
        int seg = bid >> 6, piece = bid & 63;
        int r8 = t >> 5, g = t & 31;
        const float4* base = (const float4*)prob
            + (size_t)seg * (L * 25) + (size_t)piece * (100 * 25);
        double a0 = 0, a1 = 0, a2 = 0, a3 = 0;
        if (g < 25) {
#pragma unroll
            for (int i = 0; i < 13; ++i) {       // 100 rows = 12x8 + 4
                int row = i * 8 + r8;
                if (row < 100) {
                    float4 v = base[row * 25 + g];
                    a0 += v.x; a1 += v.y; a2 += v.z; a3 += v.w;
                }
            }
        }
        __shared__ double sdata[8][100];
        if (g < 25) {
            int k4 = g * 4;
            sdata[r8][k4] = a0; sdata[r8][k4 + 1] = a1;
            sdata[r8][k4 + 2] = a2; sdata[r8][k4 + 3] = a3;
        }
        __syncthreads();
        if (t < 100) {
            double s = 0;
#pragma unroll
            for (int r = 0; r < 8; ++r) s += sdata[r][t];
            P[bid * 100 + t] = s;
        }
    }
    __threadfence();
    grid.sync();

    // ---------------- Phase B: combine + argmax (blocks 0..7) -------------
    if (bid < N) {
        __shared__ double s01[2][100];
        int n = bid;
        if (t < 200) {
            int half = t / 100, k = t - half * 100;
            const double* p = P + ((size_t)(2 * n + half) * 64) * 100 + k;
            double s = 0;
#pragma unroll 8
            for (int pc = 0; pc < 64; ++pc) s += p[pc * 100];
            s01[half][k] = s;
        }
        __syncthreads();
        if (t == 0) {
            double best = -1.0; int bi = 0;
            for (int k = 0; k < K; ++k) {
                double v = s01[0][k] * s01[1][k];
                if (v > best) { best = v; bi = k; }   // first-max tie-break
            }
            kstar[n] = bi;
        }
    }
    __threadfence();
    grid.sync();

    // ---------------- Phase C: ballot words (waves 0..799) ----------------
    {
        int wave = bid * 4 + (t >> 6);
        int lane = t & 63;
        if (wave < N * 100) {
            int n = wave / 100;
            int w = wave - n * 100;
            int l = w * 64 + lane;
            int k = kstar[n];
            float v = topics[((size_t)n * 2 * L + (size_t)l) * K + (size_t)k];
            unsigned long long bal = __ballot(v > 0.5f);
            if (lane == 0) bits[wave] = bal;
        }
    }
    __threadfence();
    grid.sync();

    // ---------------- Phase D: word-prefix scan (blocks 0..7) -------------
    if (bid < N) {
        int n = bid;
        __shared__ int cnts[100];
        if (t < 100) cnts[t] = __popcll(bits[n * 100 + t]);
        __syncthreads();
        if (t < 100) {
            int s = 0;
            for (int w = 0; w < t; ++w) s += cnts[w];
            woffs[n * 100 + t] = s;
        }
        if (t == 0) {
            int s = 0;
            for (int w = 0; w < 100; ++w) s += cnts[w];
            lenbuf[n] = s;
        }
    }
    __threadfence();
    grid.sync();

    // ---------------- Phase E: scatter + zero-fill + mask -----------------
    {
        const float4* f4 = (const float4*)feat;
        float4* o4 = (float4*)out;
        int lane = t & 63;
        int waveId = bid * 4 + (t >> 6);          // 0..4095
        for (int r = waveId; r < N * L; r += 4096) {
            int n = r / L;
            int l = r - n * L;
            unsigned long long word = bits[r >> 6];
            int len = lenbuf[n];
            int bpos = l & 63;
            if ((word >> bpos) & 1ull) {
                int d = woffs[n * 100 + (l >> 6)]
                      + __popcll(word & ((1ull << bpos) - 1ull));
                float4 v = f4[(size_t)r * 64 + lane];
                o4[((size_t)n * L + (size_t)d) * 64 + lane] = v;
            }
            if (l >= len)
                o4[(size_t)r * 64 + lane] = make_float4(0.f, 0.f, 0.f, 0.f);
        }
        // mask tail: N*L floats as float4 (L % 4 == 0)
        float4* om4 = (float4*)(out + (size_t)N * L * C);
        int tid = bid * 256 + t;
        if (tid < (N * L) / 4) {
            int n = tid / (L / 4);
            int l0 = (tid - n * (L / 4)) * 4;
            int len = lenbuf[n];
            float4 m;
            m.x = (l0     < len) ? 1.f : 0.f;
            m.y = (l0 + 1 < len) ? 1.f : 0.f;
            m.z = (l0 + 2 < len) ? 1.f : 0.f;
            m.w = (l0 + 3 < len) ? 1.f : 0.f;
            om4[tid] = m;
        }
    }
}

// ===================== fallback path (verified 5-kernel pipeline) ==========
#define CPS 32
#define RPC (L / CPS)

__global__ void kA_partial(const float* __restrict__ prob, double* __restrict__ P) {
    int b = blockIdx.x;
    int seg = b >> 5, chunk = b & 31;
    int t = threadIdx.x;
    int r8 = t >> 5, g = t & 31;
    const float4* base = (const float4*)prob
        + (size_t)seg * (L * 25) + (size_t)chunk * (RPC * 25);
    double a0 = 0, a1 = 0, a2 = 0, a3 = 0;
    if (g < 25) {
#pragma unroll
        for (int i = 0; i < RPC / 8; ++i) {
            float4 v = base[(i * 8 + r8) * 25 + g];
            a0 += v.x; a1 += v.y; a2 += v.z; a3 += v.w;
        }
    }
    __shared__ double sdata[8][100];
    if (g < 25) {
        int k4 = g * 4;
        sdata[r8][k4] = a0; sdata[r8][k4 + 1] = a1;
        sdata[r8][k4 + 2] = a2; sdata[r8][k4 + 3] = a3;
    }
    __syncthreads();
    if (t < 100) {
        double s = 0;
#pragma unroll
        for (int r = 0; r < 8; ++r) s += sdata[r][t];
        P[b * 100 + t] = s;
    }
}

__global__ void kB_argmax(const double* __restrict__ P, int* __restrict__ kstar) {
    int n = blockIdx.x, t = threadIdx.x;
    __shared__ double vbuf[100];
    if (t < 100) {
        const double* p0 = P + (size_t)(2 * n) * CPS * 100 + t;
        const double* p1 = P + (size_t)(2 * n + 1) * CPS * 100 + t;
        double s0 = 0, s1 = 0;
#pragma unroll 8
        for (int c = 0; c < CPS; ++c) { s0 += p0[c * 100]; s1 += p1[c * 100]; }
        vbuf[t] = s0 * s1;
    }
    __syncthreads();
    if (t == 0) {
        double best = -1.0; int bi = 0;
        for (int k = 0; k < K; ++k) {
            double v = vbuf[k];
            if (v > best) { best = v; bi = k; }
        }
        kstar[n] = bi;
    }
}

__global__ void kC_bits(const float* __restrict__ topics,
                        const int* __restrict__ kstar,
                        unsigned long long* __restrict__ bits) {
    int idx = blockIdx.x * 256 + threadIdx.x;
    int n = idx / L;
    int l = idx - n * L;
    int k = kstar[n];
    float v = topics[((size_t)n * 2 * L + (size_t)l) * K + (size_t)k];
    unsigned long long bal = __ballot(v > 0.5f);
    if ((threadIdx.x & 63) == 0) bits[idx >> 6] = bal;
}

__global__ void kD_scan(const unsigned long long* __restrict__ bits,
                        int* __restrict__ woffs, int* __restrict__ lenbuf,
                        float* __restrict__ out) {
    int n = blockIdx.x, t = threadIdx.x;
    __shared__ int cnts[100];
    __shared__ int len_s;
    if (t < 100) cnts[t] = __popcll(bits[n * 100 + t]);
    __syncthreads();
    if (t < 100) {
        int s = 0;
        for (int w = 0; w < t; ++w) s += cnts[w];
        woffs[n * 100 + t] = s;
    }
    if (t == 0) {
        int s = 0;
        for (int w = 0; w < 100; ++w) s += cnts[w];
        lenbuf[n] = s; len_s = s;
    }
    __syncthreads();
    int len = len_s;
    float* om = out + (size_t)N * L * C + (size_t)n * L;
    for (int idx = t; idx < L; idx += 128) om[idx] = (idx < len) ? 1.0f : 0.0f;
}

__global__ void __launch_bounds__(256)
kE_out(const float* __restrict__ feat,
       const unsigned long long* __restrict__ bits,
       const int* __restrict__ woffs, const int* __restrict__ lenbuf,
       float* __restrict__ out) {
    int r = blockIdx.x * 4 + (threadIdx.x >> 6);
    int lane = threadIdx.x & 63;
    int n = r / L;
    int l = r - n * L;
    unsigned long long word = bits[r >> 6];
    int len = lenbuf[n];
    const float4* f4 = (const float4*)feat;
    float4* o4 = (float4*)out;
    int bpos = l & 63;
    if ((word >> bpos) & 1ull) {
        int d = woffs[n * 100 + (l >> 6)]
              + __popcll(word & ((1ull << bpos) - 1ull));
        float4 v = f4[(size_t)r * 64 + lane];
        o4[((size_t)n * L + (size_t)d) * 64 + lane] = v;
    }
    if (l >= len)
        o4[(size_t)r * 64 + lane] = make_float4(0.f, 0.f, 0.f, 0.f);
}

// ===================== launch ==============================================
extern "C" void kernel_launch(void* const* d_in, const int* in_sizes, int n_in,
                              void* d_out, int out_size, void* d_ws, size_t ws_size,
                              hipStream_t stream) {
    const float* feat   = (const float*)d_in[0];
    const float* prob   = (const float*)d_in[1];
    const float* topics = (const float*)d_in[2];

    // ws layout (coop path): P[1024][100] fp64, then small int/u64 buffers.
    double* P                = (double*)d_ws;                          // 1024*100
    unsigned long long* bits = (unsigned long long*)(P + 1024 * 100);  // 800
    int* woffs               = (int*)(bits + 800);                     // 800
    int* kstar               = woffs + 800;                            // 8
    int* lenbuf              = kstar + 8;                              // 8

    float* out = (float*)d_out;

    void* args[] = { (void*)&feat, (void*)&prob, (void*)&topics,
                     (void*)&P, (void*)&bits, (void*)&woffs,
                     (void*)&kstar, (void*)&lenbuf, (void*)&out };
    hipError_t err = hipLaunchCooperativeKernel(
        reinterpret_cast<const void*>(&mega),
        dim3(1024), dim3(256), args, 0, stream);

    if (err != hipSuccess) {
        // Fallback: verified 5-kernel pipeline (uses same ws, its own layout).
        kA_partial<<<16 * CPS, 256, 0, stream>>>(prob, P);
        kB_argmax <<<N, 128, 0, stream>>>(P, kstar);
        kC_bits   <<<(N * L) / 256, 256, 0, stream>>>(topics, kstar, bits);
        kD_scan   <<<N, 128, 0, stream>>>(bits, woffs, lenbuf, out);
        kE_out    <<<(N * L) / 4, 256, 0, stream>>>(feat, bits, woffs, lenbuf, out);
    }
}

// Round 6
// 170.882 us; speedup vs baseline: 4.7995x; 4.7995x over previous
//
#include <hip/hip_runtime.h>

#define N 8
#define L 6400
#define C 256
#define K 100
#define CPS 32              // chunks per (n,half) segment
#define RPC (L / CPS)       // 200 rows per chunk

// ---- kA: per-chunk column sums. P[b][k] (fp64), b = seg*CPS + chunk --------
// (verified, unchanged) 256 threads: group g = t&31 (g<25 active) owns columns
// 4g..4g+3 of row r = i*8 + (t>>5). Contiguous float4 loads, fully unrolled.
__global__ void kA_partial(const float* __restrict__ prob, double* __restrict__ P) {
    int b = blockIdx.x;                 // 0..511
    int seg = b >> 5, chunk = b & 31;
    int t = threadIdx.x;
    int r8 = t >> 5, g = t & 31;
    const float4* base = (const float4*)prob
        + (size_t)seg * (L * 25) + (size_t)chunk * (RPC * 25);
    double a0 = 0, a1 = 0, a2 = 0, a3 = 0;
    if (g < 25) {
#pragma unroll
        for (int i = 0; i < RPC / 8; ++i) {       // 25 iters
            float4 v = base[(i * 8 + r8) * 25 + g];
            a0 += v.x; a1 += v.y; a2 += v.z; a3 += v.w;
        }
    }
    __shared__ double sdata[8][100];
    if (g < 25) {
        int k4 = g * 4;
        sdata[r8][k4] = a0; sdata[r8][k4 + 1] = a1;
        sdata[r8][k4 + 2] = a2; sdata[r8][k4 + 3] = a3;
    }
    __syncthreads();
    if (t < 100) {
        double s = 0;
#pragma unroll
        for (int r = 0; r < 8; ++r) s += sdata[r][t];
        P[b * 100 + t] = s;
    }
}

// ---- kBC: fused argmax (redundant per block) + ballot bits -----------------
// 200 blocks x 256 thr; block b: n = b/25, covers l = (b%25)*256 .. +255.
// Every block recomputes the SAME deterministic fp64 combine+argmax for its n
// (identical op order in all blocks -> identical kstar; no cross-block dep).
__global__ void __launch_bounds__(256)
kBC(const double* __restrict__ P, const float* __restrict__ topics,
    unsigned long long* __restrict__ bits) {
    int b = blockIdx.x, t = threadIdx.x;
    int n = b / 25, blk = b - n * 25;
    __shared__ double vbuf[100];
    __shared__ int ks_s;
    if (t < 100) {
        const double* p0 = P + (size_t)(2 * n) * CPS * 100 + t;
        const double* p1 = P + (size_t)(2 * n + 1) * CPS * 100 + t;
        double s0 = 0, s1 = 0;
#pragma unroll 8
        for (int c = 0; c < CPS; ++c) { s0 += p0[c * 100]; s1 += p1[c * 100]; }
        vbuf[t] = s0 * s1;
    }
    __syncthreads();
    if (t == 0) {
        double best = -1.0; int bi = 0;
        for (int k = 0; k < K; ++k) {
            double v = vbuf[k];
            if (v > best) { best = v; bi = k; }   // strict '>' = first-max
        }
        ks_s = bi;
    }
    __syncthreads();
    int k = ks_s;
    int l = blk * 256 + t;
    float v = topics[((size_t)n * 2 * L + (size_t)l) * K + (size_t)k];
    unsigned long long bal = __ballot(v > 0.5f);
    if ((t & 63) == 0) bits[n * 100 + (l >> 6)] = bal;
}

// ---- kDE: fused scan (redundant per block) + scatter + zero + mask ---------
// 800 blocks x 256 thr; block b: n = b/100, word w = b%100 -> rows
// l = w*64 .. w*64+63 (exactly one bits word). Per-block LDS scan of the
// n's 100 popcounts gives pre (words < w) and len; then verified scatter.
__global__ void __launch_bounds__(256)
kDE(const float* __restrict__ feat, const unsigned long long* __restrict__ bits,
    float* __restrict__ out) {
    int b = blockIdx.x, t = threadIdx.x;
    int n = b / 100, w = b - n * 100;
    __shared__ unsigned long long sb[100];
    __shared__ int sA[128], sB[128];
    if (t < 100) sb[t] = bits[n * 100 + t];
    __syncthreads();
    int c = (t < 100) ? __popcll(sb[t]) : 0;
    if (t < 128) sA[t] = c;
    __syncthreads();
    // Hillis-Steele inclusive scan over 128 (7 steps, ping-pong LDS)
    int* src = sA; int* dst = sB;
    for (int off = 1; off < 128; off <<= 1) {
        if (t < 128) dst[t] = src[t] + ((t >= off) ? src[t - off] : 0);
        __syncthreads();
        int* tmp = src; src = dst; dst = tmp;
    }
    int len = src[127];                       // total popcount = len(n)
    int pre = (w > 0) ? src[w - 1] : 0;       // selected rows before word w
    unsigned long long word = sb[w];

    const float4* f4 = (const float4*)feat;
    float4* o4 = (float4*)out;
    int lane = t & 63, wv = t >> 6;           // 4 waves x 16 rows each
#pragma unroll 4
    for (int j = 0; j < 16; ++j) {
        int li = wv * 16 + j;                 // bit position 0..63
        int l = w * 64 + li;
        size_t r = (size_t)n * L + l;
        if ((word >> li) & 1ull) {
            int d = pre + __popcll(word & ((1ull << li) - 1ull));
            float4 v = f4[r * 64 + lane];
            o4[((size_t)n * L + (size_t)d) * 64 + lane] = v;
        }
        if (l >= len)
            o4[r * 64 + lane] = make_float4(0.f, 0.f, 0.f, 0.f);
    }
    // mask: 64 floats for this block's rows, coalesced
    if (t < 64) {
        int l = w * 64 + t;
        out[(size_t)N * L * C + (size_t)n * L + l] = (l < len) ? 1.0f : 0.0f;
    }
}

// ===================== launch ==============================================
extern "C" void kernel_launch(void* const* d_in, const int* in_sizes, int n_in,
                              void* d_out, int out_size, void* d_ws, size_t ws_size,
                              hipStream_t stream) {
    const float* feat   = (const float*)d_in[0];
    const float* prob   = (const float*)d_in[1];
    const float* topics = (const float*)d_in[2];

    // ws layout (~416 KB): P[512][100] fp64, bits[800] u64.
    double* P                = (double*)d_ws;                        // 512*100
    unsigned long long* bits = (unsigned long long*)(P + 512 * 100); // 800

    float* out = (float*)d_out;

    kA_partial<<<16 * CPS, 256, 0, stream>>>(prob, P);
    kBC       <<<N * 25, 256, 0, stream>>>(P, topics, bits);
    kDE       <<<N * 100, 256, 0, stream>>>(feat, bits, out);
}

// Round 8
// 169.134 us; speedup vs baseline: 4.8491x; 1.0103x over previous
//
#include <hip/hip_runtime.h>

#define N 8
#define L 6400
#define C 256
#define K 100
#define CPS 32              // chunks per (n,half) segment
#define RPC (L / CPS)       // 200 rows per chunk

// ---- kA: per-chunk column sums. P[b][k] (fp64), b = seg*CPS + chunk --------
// 512 blocks x 512 threads. Thread t<500 loads float4 idx = j*500 + t of the
// block's 5000-float4 chunk (perfectly linear: wave reads 1KB contiguous).
// 500 % 25 == 0 -> column group g = t%25 is constant per thread; accumulate
// columns 4g..4g+3 across the thread's 10 rows-slots, LDS-reduce 20 partials.
__global__ void __launch_bounds__(512)
kA_partial(const float* __restrict__ prob, double* __restrict__ P) {
    int b = blockIdx.x;                 // 0..511
    int seg = b >> 5, chunk = b & 31;
    int t = threadIdx.x;
    const float4* base = (const float4*)prob
        + (size_t)seg * (L * 25) + (size_t)chunk * (RPC * 25);
    double a0 = 0, a1 = 0, a2 = 0, a3 = 0;
    int g = t % 25, rg = t / 25;        // col group (fixed), partial row 0..19
    if (t < 500) {
#pragma unroll
        for (int j = 0; j < 10; ++j) {  // 10 x 500 float4 = 200 rows x 25
            float4 v = base[j * 500 + t];
            a0 += v.x; a1 += v.y; a2 += v.z; a3 += v.w;
        }
    }
    __shared__ double sdata[20][100];
    if (t < 500) {
        int k4 = g * 4;
        sdata[rg][k4] = a0; sdata[rg][k4 + 1] = a1;
        sdata[rg][k4 + 2] = a2; sdata[rg][k4 + 3] = a3;
    }
    __syncthreads();
    if (t < 100) {
        double s = 0;
#pragma unroll
        for (int r = 0; r < 20; ++r) s += sdata[r][t];
        P[b * 100 + t] = s;
    }
}

// ---- kBC: fused argmax (redundant per block) + ballot bits (verified R6) ---
// 200 blocks x 256 thr; block b: n = b/25, covers l = (b%25)*256 .. +255.
// Every block recomputes the SAME deterministic fp64 combine+argmax for its n
// (identical op order in all blocks -> identical kstar; no cross-block dep).
__global__ void __launch_bounds__(256)
kBC(const double* __restrict__ P, const float* __restrict__ topics,
    unsigned long long* __restrict__ bits) {
    int b = blockIdx.x, t = threadIdx.x;
    int n = b / 25, blk = b - n * 25;
    __shared__ double vbuf[100];
    __shared__ int ks_s;
    if (t < 100) {
        const double* p0 = P + (size_t)(2 * n) * CPS * 100 + t;
        const double* p1 = P + (size_t)(2 * n + 1) * CPS * 100 + t;
        double s0 = 0, s1 = 0;
#pragma unroll 8
        for (int c = 0; c < CPS; ++c) { s0 += p0[c * 100]; s1 += p1[c * 100]; }
        vbuf[t] = s0 * s1;
    }
    __syncthreads();
    if (t == 0) {
        double best = -1.0; int bi = 0;
        for (int k = 0; k < K; ++k) {
            double v = vbuf[k];
            if (v > best) { best = v; bi = k; }   // strict '>' = first-max
        }
        ks_s = bi;
    }
    __syncthreads();
    int k = ks_s;
    int l = blk * 256 + t;
    float v = topics[((size_t)n * 2 * L + (size_t)l) * K + (size_t)k];
    unsigned long long bal = __ballot(v > 0.5f);
    if ((t & 63) == 0) bits[n * 100 + (l >> 6)] = bal;
}

// ---- kDE: fused scan (redundant per block) + scatter + zero + mask ---------
// 800 blocks x 512 thr (8 waves x 8 rows); block b: n = b/100, word w = b%100
// -> rows l = w*64 .. +63. Per-block LDS scan of the n's 100 popcounts gives
// pre (words < w) and len; then verified scatter/zero/mask.
__global__ void __launch_bounds__(512)
kDE(const float* __restrict__ feat, const unsigned long long* __restrict__ bits,
    float* __restrict__ out) {
    int b = blockIdx.x, t = threadIdx.x;
    int n = b / 100, w = b - n * 100;
    __shared__ unsigned long long sb[100];
    __shared__ int sA[128], sB[128];
    if (t < 100) sb[t] = bits[n * 100 + t];
    __syncthreads();
    if (t < 128) sA[t] = (t < 100) ? __popcll(sb[t]) : 0;
    __syncthreads();
    // Hillis-Steele inclusive scan over 128 (7 steps, ping-pong LDS)
    int* src = sA; int* dst = sB;
    for (int off = 1; off < 128; off <<= 1) {
        if (t < 128) dst[t] = src[t] + ((t >= off) ? src[t - off] : 0);
        __syncthreads();
        int* tmp = src; src = dst; dst = tmp;
    }
    int len = src[127];                       // total popcount = len(n)
    int pre = (w > 0) ? src[w - 1] : 0;       // selected rows before word w
    unsigned long long word = sb[w];

    const float4* f4 = (const float4*)feat;
    float4* o4 = (float4*)out;
    int lane = t & 63, wv = t >> 6;           // 8 waves x 8 rows each
#pragma unroll
    for (int j = 0; j < 8; ++j) {
        int li = wv * 8 + j;                  // bit position 0..63
        int l = w * 64 + li;
        size_t r = (size_t)n * L + l;
        if ((word >> li) & 1ull) {
            int d = pre + __popcll(word & ((1ull << li) - 1ull));
            float4 v = f4[r * 64 + lane];
            o4[((size_t)n * L + (size_t)d) * 64 + lane] = v;
        }
        if (l >= len)
            o4[r * 64 + lane] = make_float4(0.f, 0.f, 0.f, 0.f);
    }
    // mask: 64 floats for this block's rows, coalesced
    if (t < 64) {
        int l = w * 64 + t;
        out[(size_t)N * L * C + (size_t)n * L + l] = (l < len) ? 1.0f : 0.0f;
    }
}

// ===================== launch ==============================================
extern "C" void kernel_launch(void* const* d_in, const int* in_sizes, int n_in,
                              void* d_out, int out_size, void* d_ws, size_t ws_size,
                              hipStream_t stream) {
    const float* feat   = (const float*)d_in[0];
    const float* prob   = (const float*)d_in[1];
    const float* topics = (const float*)d_in[2];

    // ws layout (~416 KB): P[512][100] fp64, bits[800] u64.
    double* P                = (double*)d_ws;                        // 512*100
    unsigned long long* bits = (unsigned long long*)(P + 512 * 100); // 800

    float* out = (float*)d_out;

    kA_partial<<<16 * CPS, 512, 0, stream>>>(prob, P);
    kBC       <<<N * 25, 256, 0, stream>>>(P, topics, bits);
    kDE       <<<N * 100, 512, 0, stream>>>(feat, bits, out);
}

// Round 12
// 168.874 us; speedup vs baseline: 4.8566x; 1.0015x over previous
//
#include <hip/hip_runtime.h>

#define N 8
#define L 6400
#define C 256
#define K 100
#define CPS 32              // chunks per (n,half) segment
#define RPC (L / CPS)       // 200 rows per chunk

// ---- kA: per-chunk column sums. P[b][k] (fp64), b = seg*CPS + chunk --------
// (R8-verified, unchanged) 512 blocks x 512 threads. Thread t<500 loads float4
// idx = j*500 + t of the block's 5000-float4 chunk (wave reads 1KB contiguous).
// 500 % 25 == 0 -> column group g = t%25 is constant per thread.
__global__ void __launch_bounds__(512)
kA_partial(const float* __restrict__ prob, double* __restrict__ P) {
    int b = blockIdx.x;                 // 0..511
    int seg = b >> 5, chunk = b & 31;
    int t = threadIdx.x;
    const float4* base = (const float4*)prob
        + (size_t)seg * (L * 25) + (size_t)chunk * (RPC * 25);
    double a0 = 0, a1 = 0, a2 = 0, a3 = 0;
    int g = t % 25, rg = t / 25;        // col group (fixed), partial row 0..19
    if (t < 500) {
#pragma unroll
        for (int j = 0; j < 10; ++j) {  // 10 x 500 float4 = 200 rows x 25
            float4 v = base[j * 500 + t];
            a0 += v.x; a1 += v.y; a2 += v.z; a3 += v.w;
        }
    }
    __shared__ double sdata[20][100];
    if (t < 500) {
        int k4 = g * 4;
        sdata[rg][k4] = a0; sdata[rg][k4 + 1] = a1;
        sdata[rg][k4 + 2] = a2; sdata[rg][k4 + 3] = a3;
    }
    __syncthreads();
    if (t < 100) {
        double s = 0;
#pragma unroll
        for (int r = 0; r < 20; ++r) s += sdata[r][t];
        P[b * 100 + t] = s;
    }
}

// ---- kBC: fused argmax (redundant per block, wave-parallel) + ballot -------
// 200 blocks x 256 thr; block b: n = b/25, covers l = (b%25)*256 .. +255.
// Combine is bit-identical in every block; argmax via 64-lane butterfly on
// (value, index): ov>bv, or ov==bv && oi<bi  ==  first-max tie-break.
__global__ void __launch_bounds__(256)
kBC(const double* __restrict__ P, const float* __restrict__ topics,
    unsigned long long* __restrict__ bits) {
    int b = blockIdx.x, t = threadIdx.x;
    int n = b / 25, blk = b - n * 25;
    __shared__ double vbuf[100];
    __shared__ int ks_s;
    if (t < 100) {
        const double* p0 = P + (size_t)(2 * n) * CPS * 100 + t;
        const double* p1 = P + (size_t)(2 * n + 1) * CPS * 100 + t;
        double s0 = 0, s1 = 0;
#pragma unroll 8
        for (int c = 0; c < CPS; ++c) { s0 += p0[c * 100]; s1 += p1[c * 100]; }
        vbuf[t] = s0 * s1;
    }
    __syncthreads();
    if (t < 64) {
        double bv; int bi;
        if (t < 36) {                       // t and t+64 both < 100
            double v0 = vbuf[t], v1 = vbuf[t + 64];
            bv = (v1 > v0) ? v1 : v0;       // equal -> keep smaller idx t
            bi = (v1 > v0) ? t + 64 : t;
        } else {                            // only t valid
            bv = vbuf[t]; bi = t;
        }
        for (int off = 32; off > 0; off >>= 1) {
            double ov = __shfl_xor(bv, off, 64);
            int    oi = __shfl_xor(bi, off, 64);
            if (ov > bv || (ov == bv && oi < bi)) { bv = ov; bi = oi; }
        }
        if (t == 0) ks_s = bi;
    }
    __syncthreads();
    int k = ks_s;
    int l = blk * 256 + t;
    float v = topics[((size_t)n * 2 * L + (size_t)l) * K + (size_t)k];
    unsigned long long bal = __ballot(v > 0.5f);
    if ((t & 63) == 0) bits[n * 100 + (l >> 6)] = bal;
}

// ---- kDE: fused scan (single-wave shuffle) + scatter + zero + mask ---------
// 800 blocks x 512 thr (8 waves x 8 rows); block b: n = b/100, word w = b%100
// -> rows l = w*64 .. +63. Wave 0 scans the n's 100 popcounts via 6-step
// __shfl_up (lanes 0..49 hold word pairs), writes 100 exclusive prefixes +
// len to LDS; one barrier; then verified scatter/zero/mask.
__global__ void __launch_bounds__(512)
kDE(const float* __restrict__ feat, const unsigned long long* __restrict__ bits,
    float* __restrict__ out) {
    int b = blockIdx.x, t = threadIdx.x;
    int n = b / 100, w = b - n * 100;
    __shared__ unsigned long long sb[100];
    __shared__ int pref[100];           // exclusive prefix (rows before word)
    __shared__ int len_s;
    if (t < 100) sb[t] = bits[n * 100 + t];
    __syncthreads();
    if (t < 64) {
        int c0 = (t < 50) ? __popcll(sb[2 * t])     : 0;
        int c1 = (t < 50) ? __popcll(sb[2 * t + 1]) : 0;
        int c2 = c0 + c1;
        int s = c2;                     // inclusive scan over 64 lanes
        for (int off = 1; off < 64; off <<= 1) {
            int up = __shfl_up(s, off, 64);
            if (t >= off) s += up;
        }
        if (t < 50) {
            int excl = s - c2;          // words before 2t
            pref[2 * t]     = excl;
            pref[2 * t + 1] = excl + c0;
        }
        if (t == 63) len_s = s;         // total of all 100 words
    }
    __syncthreads();
    int len = len_s;
    int pre = pref[w];
    unsigned long long word = sb[w];

    const float4* f4 = (const float4*)feat;
    float4* o4 = (float4*)out;
    int lane = t & 63, wv = t >> 6;     // 8 waves x 8 rows each
#pragma unroll
    for (int j = 0; j < 8; ++j) {
        int li = wv * 8 + j;            // bit position 0..63
        int l = w * 64 + li;
        size_t r = (size_t)n * L + l;
        if ((word >> li) & 1ull) {
            int d = pre + __popcll(word & ((1ull << li) - 1ull));
            float4 v = f4[r * 64 + lane];
            o4[((size_t)n * L + (size_t)d) * 64 + lane] = v;
        }
        if (l >= len)
            o4[r * 64 + lane] = make_float4(0.f, 0.f, 0.f, 0.f);
    }
    // mask: 64 floats for this block's rows, coalesced
    if (t < 64) {
        int l = w * 64 + t;
        out[(size_t)N * L * C + (size_t)n * L + l] = (l < len) ? 1.0f : 0.0f;
    }
}

// ===================== launch ==============================================
extern "C" void kernel_launch(void* const* d_in, const int* in_sizes, int n_in,
                              void* d_out, int out_size, void* d_ws, size_t ws_size,
                              hipStream_t stream) {
    const float* feat   = (const float*)d_in[0];
    const float* prob   = (const float*)d_in[1];
    const float* topics = (const float*)d_in[2];

    // ws layout (~416 KB): P[512][100] fp64, bits[800] u64.
    double* P                = (double*)d_ws;                        // 512*100
    unsigned long long* bits = (unsigned long long*)(P + 512 * 100); // 800

    float* out = (float*)d_out;

    kA_partial<<<16 * CPS, 512, 0, stream>>>(prob, P);
    kBC       <<<N * 25, 256, 0, stream>>>(P, topics, bits);
    kDE       <<<N * 100, 512, 0, stream>>>(feat, bits, out);
}